// Round 11
// baseline (5076.262 us; speedup 1.0000x reference)
//
#include <hip/hip_runtime.h>
#include <hip/hip_bf16.h>

#define Bsz   1024
#define Lseq  50
#define Din   4
#define Hd    512
#define Tlen  30
#define NWG   256

typedef __hip_bfloat16 bf16;
typedef short s16x8 __attribute__((ext_vector_type(8)));
typedef short s16x4 __attribute__((ext_vector_type(4)));
typedef float f32x4 __attribute__((ext_vector_type(4)));

__device__ __forceinline__ float bf2f(bf16 x){ return __bfloat162float(x); }
__device__ __forceinline__ bf16  f2bf(float x){ return __float2bfloat16(x); }
__device__ __forceinline__ float bfbits2f(short u){
    union { unsigned int ui; float f; } v;
    v.ui = ((unsigned int)(unsigned short)u) << 16;
    return v.f;
}
__device__ __forceinline__ short f2bfbits(float x){
    bf16 h = f2bf(x); short s; __builtin_memcpy(&s, &h, 2); return s;
}
__device__ __forceinline__ float sigm(float x){ return 1.0f/(1.0f + __expf(-x)); }
__device__ __forceinline__ float ftanh(float x){
    const float e = __expf(2.0f*x);
    return 1.0f - 2.0f/(e + 1.0f);
}
__device__ __forceinline__ unsigned long long pack4(float a, float b, float c, float d){
    unsigned long long v0 = (unsigned short)f2bfbits(a);
    unsigned long long v1 = (unsigned short)f2bfbits(b);
    unsigned long long v2 = (unsigned short)f2bfbits(c);
    unsigned long long v3 = (unsigned short)f2bfbits(d);
    return v0 | (v1 << 16) | (v2 << 32) | (v3 << 48);
}

// ---- system-scope (sc0/sc1) coherent accesses, compiler-tracked ----
__device__ __forceinline__ unsigned long long sc_ld64(const void* p){
    return __hip_atomic_load((const unsigned long long*)p,
                             __ATOMIC_RELAXED, __HIP_MEMORY_SCOPE_SYSTEM);
}
__device__ __forceinline__ s16x4 sc_ld64v(const void* p){
    unsigned long long u = sc_ld64(p);
    s16x4 r; __builtin_memcpy(&r, &u, 8); return r;
}
__device__ __forceinline__ s16x8 sc_ld128(const void* p){
    unsigned long long a = sc_ld64(p);
    unsigned long long b = sc_ld64((const char*)p + 8);
    s16x8 r;
    __builtin_memcpy(&r, &a, 8);
    __builtin_memcpy((char*)&r + 8, &b, 8);
    return r;
}
__device__ __forceinline__ void sc_st64(void* p, unsigned long long v){
    __hip_atomic_store((unsigned long long*)p, v,
                       __ATOMIC_RELAXED, __HIP_MEMORY_SCOPE_SYSTEM);
}

// ---------------- ws layout (bytes) ----------------
#define OFF_ABUF0   (0u)
#define OFF_ABUF1   (2u<<20)
#define OFF_ATTNAP  (8u<<20)
#define OFF_XDEC    (9u<<20)
#define OFF_FLAG    ((9u<<20) + (16u<<10))
#define OFF_COMBWR  ((9u<<20) + (32u<<10))
#define OFF_ATTNWR  ((9u<<20) + (600u<<10))
#define OFF_FLAGS   ((9u<<20) + (704u<<10))
#define OFF_WCACHE  (10u<<20)
#define OFF_ENCOUT  (18u<<20)

// wcache element offsets (bf16 elements), 8-elem aligned per array
#define WC_INPUT 0
#define WC_EWIH  204800
#define WC_EWHH  212992
#define WC_EBIH  1261568
#define WC_EBHH  1263616
#define WC_AW    1265664
#define WC_AB    1291464
#define WC_CW    1291520
#define WC_CB    1555712
#define WC_DWIH  1556224
#define WC_DWHH  2604800
#define WC_DBIH  3653376
#define WC_DBHH  3655424
#define WC_OW    3657472
#define WC_OB    3659520
#define WC_TOTAL 3659524

__device__ __constant__ int WOFF[15] = {
    WC_INPUT, WC_EWIH, WC_EWHH, WC_EBIH, WC_EBHH, WC_AW, WC_AB, WC_CW,
    WC_CB, WC_DWIH, WC_DWHH, WC_DBIH, WC_DBHH, WC_OW, WC_OB };
__device__ __constant__ int WNUM[15] = {
    204800, 8192, 1048576, 2048, 2048, 25800, 50, 264192,
    512, 1048576, 1048576, 2048, 2048, 2048, 4 };

struct Ptrs15 { const void* p[15]; };

__global__ void probe_kernel(const unsigned int* __restrict__ w, int* flag){
    __shared__ int cnt;
    if (threadIdx.x == 0) cnt = 0;
    __syncthreads();
    int c = 0;
    for (int i = threadIdx.x; i < 4096; i += 256){
        unsigned e = (w[i] >> 7) & 0xFFu;
        c += (e >= 0x80u) ? 1 : 0;
    }
    atomicAdd(&cnt, c);
    __syncthreads();
    if (threadIdx.x == 0) *flag = (cnt > 400) ? 1 : 0;
}

__global__ __launch_bounds__(256) void convert_kernel(
    Ptrs15 srcs, const int* __restrict__ flag, bf16* __restrict__ dst)
{
    const int f = *flag;
    for (int idx = blockIdx.x*256 + threadIdx.x; idx < WC_TOTAL;
         idx += gridDim.x*256){
        int a = 0;
#pragma unroll
        for (int j = 1; j < 15; ++j) if (idx >= WOFF[j]) a = j;
        const int local = idx - WOFF[a];
        if (local >= WNUM[a]) continue;
        bf16 v;
        if (f) v = f2bf(((const float*)srcs.p[a])[local]);
        else   v = ((const bf16*)srcs.p[a])[local];
        dst[idx] = v;
    }
}

__global__ __launch_bounds__(256) void setup_kernel(
    bf16* __restrict__ Abuf0, bf16* __restrict__ Abuf1,
    bf16* __restrict__ combWr, bf16* __restrict__ attnWr,
    const bf16* __restrict__ cWc, const bf16* __restrict__ aWc)
{
    const unsigned idx = blockIdx.x*256u + threadIdx.x;
    if (idx < (unsigned)Bsz*Hd){
        const unsigned row = idx >> 9, col = idx & (Hd-1);
        const bf16 z = f2bf(0.0f);
        Abuf0[(size_t)row*1024 + Hd + col] = z;
        Abuf1[(size_t)row*1024 + Hd + col] = z;
    }
    if (idx < (unsigned)Hd*Hd)
        combWr[idx] = cWc[(size_t)(idx >> 9)*(Hd+Din) + Din + (idx & (Hd-1))];
    if (idx < (unsigned)Lseq*Hd)
        attnWr[idx] = aWc[(size_t)(idx >> 9)*(Hd+Din) + Din + (idx & (Hd-1))];
}

struct MegaP {
    const bf16 *input, *eWih, *eWhh, *ebih, *ebhh;
    const bf16 *aW, *ab, *cW, *cb, *dWih, *dWhh, *dbih, *dbhh, *oW, *ob;
    const bf16 *combWr, *attnWr;
    bf16 *A0, *A1, *encout, *attnap, *xdec;
    int *wflag, *gflag;
    const int *flag;
    void *dout;
};

// ---------------------------------------------------------------------------
// Persistent megakernel v4 — mapping-agnostic, ZERO cache-maintenance ops.
// 256 WGs x 512 thr. Tiling: mg = wg>>3 owns rows mg*32..+32; ngt = wg&7 is
// the n-tile (256 gate-cols = 64 hcols). Protocol:
//   * every cross-WG datum: sc0/sc1 write-through store (8B packed) and
//     sc0/sc1 bypass load -> L3 is the single source of truth; L2 never
//     stale because it never holds this data.
//   * read-only data (weights, input, tables): normal loads, permanently
//     warm in L2/L1 (no invalidates ever).
//   * barriers: pure flag rounds. MSYNC = 8-WG m-group (covers attnap/comb/
//     h row deps). GSYNC = 2-level global (only for the h_r reshape gather).
// enc_out slice in 100 VGPRs (ereg); c-state in registers (quad-redundant).
// ---------------------------------------------------------------------------
__global__ __launch_bounds__(512, 2) void mega_kernel(MegaP P)
{
    __shared__ short hr_s[4][Hd];          // 4 KB
    __shared__ float ctx_s[2][4][8][64];   // 16 KB
    __shared__ float aw_s[4][64];          // 1 KB

    const int wg = blockIdx.x, tid = threadIdx.x;
    const int wave = tid >> 6, lane = tid & 63;
    const int quad = lane >> 4, l15 = lane & 15;
    const int lbase = lane & ~3;
    const int f32out = *P.flag;

    const int mg = wg >> 3, ngt = wg & 7;

    int ep = 0;

    auto MSYNC = [&](){
        ++ep;
        __syncthreads();
        if (tid == 0)
            __hip_atomic_store(P.wflag + wg*16, ep, __ATOMIC_RELEASE, __HIP_MEMORY_SCOPE_SYSTEM);
        if (tid < 8){
            const int* f = P.wflag + (mg*8 + tid)*16;
            while (__hip_atomic_load(f, __ATOMIC_RELAXED, __HIP_MEMORY_SCOPE_SYSTEM) < ep)
                __builtin_amdgcn_s_sleep(1);
        }
        __syncthreads();
    };

    auto GSYNC = [&](){
        ++ep;
        __syncthreads();
        if (tid == 0)
            __hip_atomic_store(P.wflag + wg*16, ep, __ATOMIC_RELEASE, __HIP_MEMORY_SCOPE_SYSTEM);
        if (ngt == 0){
            if (tid < 8){
                const int* f = P.wflag + (mg*8 + tid)*16;
                while (__hip_atomic_load(f, __ATOMIC_RELAXED, __HIP_MEMORY_SCOPE_SYSTEM) < ep)
                    __builtin_amdgcn_s_sleep(1);
            }
            __syncthreads();
            if (tid == 0)
                __hip_atomic_store(P.gflag + mg*16, ep, __ATOMIC_RELEASE, __HIP_MEMORY_SCOPE_SYSTEM);
        }
        if (tid < 32){
            const int* f = P.gflag + tid*16;
            while (__hip_atomic_load(f, __ATOMIC_RELAXED, __HIP_MEMORY_SCOPE_SYSTEM) < ep)
                __builtin_amdgcn_s_sleep(1);
        }
        __syncthreads();
    };

    bf16* bufs[2] = { P.A0, P.A1 };

    // ---- gates tiling: 32 rows x 256 gate-cols per WG ----
    const int bm0 = mg*32, hc0 = ngt*64;

    int ng_[2];
#pragma unroll
    for (int nf = 0; nf < 2; ++nf){
        const int n = wave*32 + nf*16 + l15;          // 0..255
        ng_[nf] = (n & 3)*Hd + hc0 + (n >> 2);
    }

    // ================= ENCODER =================
    float bias_e[2], wxv_e[2][4];
#pragma unroll
    for (int nf = 0; nf < 2; ++nf){
        bias_e[nf] = bf2f(P.ebih[ng_[nf]]) + bf2f(P.ebhh[ng_[nf]]);
        const s16x4 t4 = *reinterpret_cast<const s16x4*>(P.eWih + (size_t)ng_[nf]*Din);
#pragma unroll
        for (int d = 0; d < 4; ++d) wxv_e[nf][d] = bfbits2f(t4[d]);
    }

    float creg[2][2][4];
#pragma unroll
    for (int a = 0; a < 2; ++a)
#pragma unroll
        for (int b = 0; b < 2; ++b)
#pragma unroll
            for (int r = 0; r < 4; ++r) creg[a][b][r] = 0.0f;

    for (int t = 0; t < Lseq; ++t){
        const bf16* Ain = bufs[t&1] + Hd;
        bf16* hout = bufs[(t+1)&1] + Hd;

        f32x4 acc[2][2];
#pragma unroll
        for (int mf=0; mf<2; ++mf)
#pragma unroll
            for (int nf=0; nf<2; ++nf) acc[mf][nf] = (f32x4)0.0f;

#pragma unroll
        for (int sl = 0; sl < 16; ++sl){
            s16x8 afr[2], bfr[2];
#pragma unroll
            for (int mf = 0; mf < 2; ++mf)
                afr[mf] = sc_ld128(Ain + (size_t)(bm0 + mf*16 + l15)*1024 + sl*32 + quad*8);
#pragma unroll
            for (int nf = 0; nf < 2; ++nf)
                bfr[nf] = *reinterpret_cast<const s16x8*>(
                    P.eWhh + (size_t)ng_[nf]*Hd + sl*32 + quad*8);
#pragma unroll
            for (int mf = 0; mf < 2; ++mf)
#pragma unroll
                for (int nf = 0; nf < 2; ++nf)
                    acc[mf][nf] = __builtin_amdgcn_mfma_f32_16x16x32_bf16(
                        afr[mf], bfr[nf], acc[mf][nf], 0, 0, 0);
        }

#pragma unroll
        for (int mf = 0; mf < 2; ++mf){
#pragma unroll
            for (int r = 0; r < 4; ++r){
                const int m = bm0 + mf*16 + quad*4 + r;
                const s16x4 xt = *reinterpret_cast<const s16x4*>(
                    P.input + ((size_t)m*Lseq + t)*Din);
                float xv[4];
#pragma unroll
                for (int d = 0; d < 4; ++d) xv[d] = bfbits2f(xt[d]);
#pragma unroll
                for (int nf = 0; nf < 2; ++nf){
                    float gv = acc[mf][nf][r] + bias_e[nf]
                             + xv[0]*wxv_e[nf][0] + xv[1]*wxv_e[nf][1]
                             + xv[2]*wxv_e[nf][2] + xv[3]*wxv_e[nf][3];
                    const float gi = __shfl(gv, lbase+0);
                    const float gf = __shfl(gv, lbase+1);
                    const float gg = __shfl(gv, lbase+2);
                    const float go = __shfl(gv, lbase+3);
                    // all lanes of a quad-of-4 compute identical cn/hv
                    const float cn = sigm(gf)*creg[mf][nf][r] + sigm(gi)*ftanh(gg);
                    creg[mf][nf][r] = cn;
                    const float hv = sigm(go)*ftanh(cn);
                    const float h1 = __shfl(hv, lane+4);
                    const float h2 = __shfl(hv, lane+8);
                    const float h3 = __shfl(hv, lane+12);
                    if (l15 == 0){
                        const int hcolb = hc0 + wave*8 + nf*4;
                        const unsigned long long u = pack4(hv, h1, h2, h3);
                        sc_st64(hout + (size_t)m*1024 + hcolb, u);
                        sc_st64(P.encout + ((size_t)m*Lseq + t)*Hd + hcolb, u);
                    }
                }
            }
        }
        if (t == Lseq-1) GSYNC(); else MSYNC();
    }

    // ================= DECODER setup =================
    float bias_d[2];
#pragma unroll
    for (int nf = 0; nf < 2; ++nf)
        bias_d[nf] = bf2f(P.dbih[ng_[nf]]) + bf2f(P.dbhh[ng_[nf]]);

    const int b0 = wg*4;
    const int s_uni = b0 >> 9;
    const int p0 = b0 & (Hd-1);

    // enc_out slice -> registers: wave (rr, half) holds row b0+rr, l = half*25+i
    const int rr = wave & 3, half = wave >> 2;
    s16x8 ereg[25];
    {
        const bf16* eb = P.encout + (size_t)(b0 + rr)*Lseq*Hd + lane*8;
#pragma unroll
        for (int i = 0; i < 25; ++i)
            ereg[i] = sc_ld128(eb + (size_t)(half*25 + i)*Hd);
    }

    // comb tile: wave = 16 rows x 16 cols (2 x 4 waves -> 32 rows x 64 cols)
    const int wave_m = wave >> 2, wave_n = wave & 3;
    const int ccol = hc0 + wave_n*16 + l15;
    float bias_c, wxv_c[4];
    {
        bias_c = bf2f(P.cb[ccol]);
        const s16x4 t4 = *reinterpret_cast<const s16x4*>(P.cW + (size_t)ccol*(Hd+Din));
#pragma unroll
        for (int d = 0; d < 4; ++d) wxv_c[d] = bfbits2f(t4[d]);
    }

    for (int t = 0; t < Tlen; ++t){
        const int p = t & 1;
        const bf16* hprev = bufs[p] + Hd;

        // ---- D1: hr staging (bypass) + pred(t-1) + attention + context ----
        {
            const s16x4 hv = sc_ld64v(hprev + (size_t)(2*tid + s_uni)*1024 + p0);
            hr_s[0][tid] = hv[0]; hr_s[1][tid] = hv[1];
            hr_s[2][tid] = hv[2]; hr_s[3][tid] = hv[3];
        }
        __syncthreads();

        if (wave < 4){
            const int b = b0 + wave;
            float x0, x1, x2, x3;
            if (t == 0){
                const bf16* xp = P.input + ((size_t)b*Lseq + (Lseq-1))*Din;
                x0 = bf2f(xp[0]); x1 = bf2f(xp[1]); x2 = bf2f(xp[2]); x3 = bf2f(xp[3]);
            } else {
                const s16x8 h8 = sc_ld128(hprev + (size_t)b*1024 + lane*8);
                float hvv[8];
#pragma unroll
                for (int q = 0; q < 8; ++q) hvv[q] = bfbits2f(h8[q]);
                float qd[4];
#pragma unroll
                for (int g = 0; g < 4; ++g){
                    const s16x8 w8 = *reinterpret_cast<const s16x8*>(
                        P.oW + (size_t)g*Hd + lane*8);
                    float s = 0.f;
#pragma unroll
                    for (int q = 0; q < 8; ++q) s += hvv[q]*bfbits2f(w8[q]);
                    qd[g] = s;
                }
#pragma unroll
                for (int off = 32; off; off >>= 1){
                    qd[0] += __shfl_down(qd[0], off); qd[1] += __shfl_down(qd[1], off);
                    qd[2] += __shfl_down(qd[2], off); qd[3] += __shfl_down(qd[3], off);
                }
                x0 = __shfl(qd[0],0) + bf2f(P.ob[0]);
                x1 = __shfl(qd[1],0) + bf2f(P.ob[1]);
                x2 = __shfl(qd[2],0) + bf2f(P.ob[2]);
                x3 = __shfl(qd[3],0) + bf2f(P.ob[3]);
                if (lane == 0){
                    const size_t o = ((size_t)b*Tlen + (t-1))*Din;
                    if (f32out){
                        float* dp = (float*)P.dout + o;
                        dp[0]=x0; dp[1]=x1; dp[2]=x2; dp[3]=x3;
                    } else {
                        *(unsigned long long*)((bf16*)P.dout + o) = pack4(x0,x1,x2,x3);
                    }
                }
            }
            if (lane == 0)
                sc_st64(P.xdec + (size_t)b*Din, pack4(x0,x1,x2,x3));

            float logit = -3.0e38f;
            if (lane < Lseq){
                float a0 = bf2f(P.ab[lane]);
                {
                    const bf16* wx = P.aW + (size_t)lane*(Hd+Din);
                    a0 += x0*bf2f(wx[0]) + x1*bf2f(wx[1]) + x2*bf2f(wx[2]) + x3*bf2f(wx[3]);
                }
                float a1 = 0.f, a2 = 0.f, a3 = 0.f;
                const bf16* wr = P.attnWr + (size_t)lane*Hd;
                for (int j = 0; j < Hd; j += 16){
                    float t4[4] = {0.f,0.f,0.f,0.f};
#pragma unroll
                    for (int q = 0; q < 4; ++q){
                        const s16x4 hw = *reinterpret_cast<const s16x4*>(&hr_s[wave][j + q*4]);
                        const s16x4 wv = *reinterpret_cast<const s16x4*>(wr + j + q*4);
                        t4[q] = bfbits2f(hw[0])*bfbits2f(wv[0]) + bfbits2f(hw[1])*bfbits2f(wv[1])
                              + bfbits2f(hw[2])*bfbits2f(wv[2]) + bfbits2f(hw[3])*bfbits2f(wv[3]);
                    }
                    a0 += t4[0]; a1 += t4[1]; a2 += t4[2]; a3 += t4[3];
                }
                logit = (a0 + a1) + (a2 + a3);
            }
            float mx = logit;
#pragma unroll
            for (int off = 32; off; off >>= 1) mx = fmaxf(mx, __shfl_xor(mx, off));
            const float e = (lane < Lseq) ? __expf(logit - mx) : 0.0f;
            float se = e;
#pragma unroll
            for (int off = 32; off; off >>= 1) se += __shfl_xor(se, off);
            aw_s[wave][lane] = e / se;
        }
        __syncthreads();

        // context from registers
        {
            float acc8[8] = {0.f,0.f,0.f,0.f,0.f,0.f,0.f,0.f};
#pragma unroll
            for (int i = 0; i < 25; ++i){
                const float w = aw_s[rr][half*25 + i];
#pragma unroll
                for (int q = 0; q < 8; ++q) acc8[q] += w * bfbits2f(ereg[i][q]);
            }
#pragma unroll
            for (int q = 0; q < 8; ++q) ctx_s[half][rr][q][lane] = acc8[q];
        }
        __syncthreads();

        if (wave < 4){
            const int b = b0 + wave;
            float c8[8];
#pragma unroll
            for (int q = 0; q < 8; ++q)
                c8[q] = ctx_s[0][wave][q][lane] + ctx_s[1][wave][q][lane];
            bf16* ap = P.attnap + (size_t)b*Hd + lane*8;
            sc_st64(ap,     pack4(c8[0],c8[1],c8[2],c8[3]));
            sc_st64(ap + 4, pack4(c8[4],c8[5],c8[6],c8[7]));
        }
        MSYNC();

        // ---- D2: comb GEMM (32 rows x 64 cols per WG) ----
        {
            f32x4 cacc = (f32x4)0.0f;
            const bf16* Ab = P.attnap + (size_t)(bm0 + wave_m*16 + l15)*Hd + quad*8;
#pragma unroll
            for (int kk = 0; kk < 16; ++kk){
                const s16x8 bfr = *reinterpret_cast<const s16x8*>(
                    P.combWr + (size_t)ccol*Hd + kk*32 + quad*8);
                const s16x8 afr2 = sc_ld128(Ab + kk*32);
                cacc = __builtin_amdgcn_mfma_f32_16x16x32_bf16(afr2, bfr, cacc, 0, 0, 0);
            }
            bf16* outp = bufs[p];
#pragma unroll
            for (int r = 0; r < 4; ++r){
                const int m = bm0 + wave_m*16 + quad*4 + r;
                const s16x4 xt = sc_ld64v(P.xdec + (size_t)m*Din);
                float v = cacc[r] + bias_c
                        + bfbits2f(xt[0])*wxv_c[0] + bfbits2f(xt[1])*wxv_c[1]
                        + bfbits2f(xt[2])*wxv_c[2] + bfbits2f(xt[3])*wxv_c[3];
                v = fmaxf(v, 0.0f);
                const float v1 = __shfl(v, lbase+1);
                const float v2 = __shfl(v, lbase+2);
                const float v3 = __shfl(v, lbase+3);
                if ((lane & 3) == 0)
                    sc_st64(outp + (size_t)m*1024 + (ccol & ~3), pack4(v,v1,v2,v3));
            }
        }
        MSYNC();

        // ---- D3: dec gates (K=1024, weights from L2) ----
        {
            const bf16* Ain = bufs[p];
            bf16* hout = bufs[p^1] + Hd;
            f32x4 acc[2][2];
#pragma unroll
            for (int mf=0; mf<2; ++mf)
#pragma unroll
                for (int nf=0; nf<2; ++nf) acc[mf][nf] = (f32x4)0.0f;

            const bf16* Wh[2] = { P.dWih, P.dWhh };
#pragma unroll
            for (int h = 0; h < 2; ++h){
#pragma unroll
                for (int sl = 0; sl < 16; ++sl){
                    s16x8 afr[2], bfr[2];
#pragma unroll
                    for (int mf = 0; mf < 2; ++mf)
                        afr[mf] = sc_ld128(Ain + (size_t)(bm0 + mf*16 + l15)*1024
                                           + h*Hd + sl*32 + quad*8);
#pragma unroll
                    for (int nf = 0; nf < 2; ++nf)
                        bfr[nf] = *reinterpret_cast<const s16x8*>(
                            Wh[h] + (size_t)ng_[nf]*Hd + sl*32 + quad*8);
#pragma unroll
                    for (int mf = 0; mf < 2; ++mf)
#pragma unroll
                        for (int nf = 0; nf < 2; ++nf)
                            acc[mf][nf] = __builtin_amdgcn_mfma_f32_16x16x32_bf16(
                                afr[mf], bfr[nf], acc[mf][nf], 0, 0, 0);
                }
            }

#pragma unroll
            for (int mf = 0; mf < 2; ++mf){
#pragma unroll
                for (int r = 0; r < 4; ++r){
                    const int m = bm0 + mf*16 + quad*4 + r;
#pragma unroll
                    for (int nf = 0; nf < 2; ++nf){
                        float gv = acc[mf][nf][r] + bias_d[nf];
                        const float gi = __shfl(gv, lbase+0);
                        const float gf = __shfl(gv, lbase+1);
                        const float gg = __shfl(gv, lbase+2);
                        const float go = __shfl(gv, lbase+3);
                        const float cn = sigm(gf)*creg[mf][nf][r] + sigm(gi)*ftanh(gg);
                        creg[mf][nf][r] = cn;
                        const float hv = sigm(go)*ftanh(cn);
                        const float h1 = __shfl(hv, lane+4);
                        const float h2 = __shfl(hv, lane+8);
                        const float h3 = __shfl(hv, lane+12);
                        if (l15 == 0){
                            const int hcolb = hc0 + wave*8 + nf*4;
                            sc_st64(hout + (size_t)m*1024 + hcolb, pack4(hv,h1,h2,h3));
                        }
                    }
                }
            }
        }
        GSYNC();
    }

    // ---- final pred (t = T-1) ----
    if (wave < 4){
        const int b = b0 + wave;
        const bf16* hb = bufs[Tlen & 1] + Hd + (size_t)b*1024;
        const s16x8 h8 = sc_ld128(hb + lane*8);
        float hvv[8];
#pragma unroll
        for (int q = 0; q < 8; ++q) hvv[q] = bfbits2f(h8[q]);
        float qd[4];
#pragma unroll
        for (int g = 0; g < 4; ++g){
            const s16x8 w8 = *reinterpret_cast<const s16x8*>(P.oW + (size_t)g*Hd + lane*8);
            float s = 0.f;
#pragma unroll
            for (int q = 0; q < 8; ++q) s += hvv[q]*bfbits2f(w8[q]);
            qd[g] = s;
        }
#pragma unroll
        for (int off = 32; off; off >>= 1){
            qd[0] += __shfl_down(qd[0], off); qd[1] += __shfl_down(qd[1], off);
            qd[2] += __shfl_down(qd[2], off); qd[3] += __shfl_down(qd[3], off);
        }
        if (lane == 0){
            const size_t o = ((size_t)b*Tlen + (Tlen-1))*Din;
            const float r0 = qd[0] + bf2f(P.ob[0]), r1 = qd[1] + bf2f(P.ob[1]);
            const float r2 = qd[2] + bf2f(P.ob[2]), r3 = qd[3] + bf2f(P.ob[3]);
            if (f32out){
                float* dp = (float*)P.dout + o;
                dp[0]=r0; dp[1]=r1; dp[2]=r2; dp[3]=r3;
            } else {
                *(unsigned long long*)((bf16*)P.dout + o) = pack4(r0,r1,r2,r3);
            }
        }
    }
}

extern "C" void kernel_launch(void* const* d_in, const int* in_sizes, int n_in,
                              void* d_out, int out_size, void* d_ws, size_t ws_size,
                              hipStream_t stream)
{
    char* ws = (char*)d_ws;
    bf16*  Abuf0   = (bf16*)(ws + OFF_ABUF0);
    bf16*  Abuf1   = (bf16*)(ws + OFF_ABUF1);
    bf16*  attnap  = (bf16*)(ws + OFF_ATTNAP);
    bf16*  xdec    = (bf16*)(ws + OFF_XDEC);
    int*   flag    = (int*)(ws + OFF_FLAG);
    bf16*  combWr  = (bf16*)(ws + OFF_COMBWR);
    bf16*  attnWr  = (bf16*)(ws + OFF_ATTNWR);
    int*   flags   = (int*)(ws + OFF_FLAGS);
    bf16*  wc      = (bf16*)(ws + OFF_WCACHE);
    bf16*  enc_out = (bf16*)(ws + OFF_ENCOUT);

    hipMemsetAsync(flags, 0, 20480, stream);

    probe_kernel<<<1, 256, 0, stream>>>((const unsigned int*)d_in[3], flag);

    Ptrs15 srcs;
    srcs.p[0]=d_in[0];  srcs.p[1]=d_in[2];  srcs.p[2]=d_in[3];  srcs.p[3]=d_in[4];
    srcs.p[4]=d_in[5];  srcs.p[5]=d_in[6];  srcs.p[6]=d_in[7];  srcs.p[7]=d_in[8];
    srcs.p[8]=d_in[9];  srcs.p[9]=d_in[10]; srcs.p[10]=d_in[11];srcs.p[11]=d_in[12];
    srcs.p[12]=d_in[13];srcs.p[13]=d_in[14];srcs.p[14]=d_in[15];
    convert_kernel<<<1024, 256, 0, stream>>>(srcs, flag, wc);

    setup_kernel<<<2048, 256, 0, stream>>>(Abuf0, Abuf1, combWr, attnWr,
                                           wc+WC_CW, wc+WC_AW);

    MegaP P;
    P.input = wc+WC_INPUT; P.eWih = wc+WC_EWIH; P.eWhh = wc+WC_EWHH;
    P.ebih = wc+WC_EBIH;   P.ebhh = wc+WC_EBHH;
    P.aW = wc+WC_AW;  P.ab = wc+WC_AB;  P.cW = wc+WC_CW;  P.cb = wc+WC_CB;
    P.dWih = wc+WC_DWIH; P.dWhh = wc+WC_DWHH; P.dbih = wc+WC_DBIH; P.dbhh = wc+WC_DBHH;
    P.oW = wc+WC_OW;  P.ob = wc+WC_OB;
    P.combWr = combWr; P.attnWr = attnWr;
    P.A0 = Abuf0; P.A1 = Abuf1; P.encout = enc_out; P.attnap = attnap; P.xdec = xdec;
    P.wflag = flags; P.gflag = flags + 256*16;
    P.flag = flag; P.dout = d_out;

    mega_kernel<<<NWG, 512, 0, stream>>>(P);
}